// Round 5
// baseline (441.896 us; speedup 1.0000x reference)
//
#include <hip/hip_runtime.h>
#include <stdint.h>

#define N_T   3072
#define D_T   128
#define K_T   1536
#define FS_T  192
#define RES_T 1345
#define TOT_T (RES_T * FS_T)   // 258240
#define TINYF 1.17549435e-38f
#define NBLK  256
#define NTHR  512
#define NWAVE 2048             // NBLK * NTHR/64

// ---------------- wave-level reductions (64 lanes, fixed order, deterministic) ----------------

__device__ __forceinline__ double wsumd(double v) {
  v += __shfl_xor(v, 1);  v += __shfl_xor(v, 2);  v += __shfl_xor(v, 4);
  v += __shfl_xor(v, 8);  v += __shfl_xor(v, 16); v += __shfl_xor(v, 32);
  return v;
}
__device__ __forceinline__ double wmaxd(double v) {
  v = fmax(v, __shfl_xor(v, 1));  v = fmax(v, __shfl_xor(v, 2));
  v = fmax(v, __shfl_xor(v, 4));  v = fmax(v, __shfl_xor(v, 8));
  v = fmax(v, __shfl_xor(v, 16)); v = fmax(v, __shfl_xor(v, 32));
  return v;
}
__device__ __forceinline__ float wsumf(float v) {
  v += __shfl_xor(v, 1);  v += __shfl_xor(v, 2);  v += __shfl_xor(v, 4);
  v += __shfl_xor(v, 8);  v += __shfl_xor(v, 16); v += __shfl_xor(v, 32);
  return v;
}
__device__ __forceinline__ float wmaxf(float v) {
  v = fmaxf(v, __shfl_xor(v, 1));  v = fmaxf(v, __shfl_xor(v, 2));
  v = fmaxf(v, __shfl_xor(v, 4));  v = fmaxf(v, __shfl_xor(v, 8));
  v = fmaxf(v, __shfl_xor(v, 16)); v = fmaxf(v, __shfl_xor(v, 32));
  return v;
}
__device__ __forceinline__ int wsumi(int v) {
  v += __shfl_xor(v, 1);  v += __shfl_xor(v, 2);  v += __shfl_xor(v, 4);
  v += __shfl_xor(v, 8);  v += __shfl_xor(v, 16); v += __shfl_xor(v, 32);
  return v;
}

// ---------------- device-scope grid barrier (one-shot, ws-backed, zeroed per launch) ----------------
// Safe: grid == 256 blocks <= 256 CUs -> all blocks resident concurrently.
__device__ __forceinline__ void grid_barrier(int* bar, int b) {
  __threadfence();                 // release this thread's writes to agent scope
  __syncthreads();
  if (threadIdx.x == 0) {
    int old = __hip_atomic_fetch_add(&bar[b], 1, __ATOMIC_ACQ_REL, __HIP_MEMORY_SCOPE_AGENT);
    if (old == NBLK - 1) {
      __hip_atomic_store(&bar[8 + b], 1, __ATOMIC_RELEASE, __HIP_MEMORY_SCOPE_AGENT);
    } else {
      while (__hip_atomic_load(&bar[8 + b], __ATOMIC_ACQUIRE, __HIP_MEMORY_SCOPE_AGENT) == 0) {
        __builtin_amdgcn_s_sleep(2);
      }
    }
  }
  __syncthreads();
  __threadfence();                 // acquire: invalidate stale cached data
}

// ---------------- threefry-2x32 (exact JAX bits, partitionable layout) ----------------

__device__ __forceinline__ uint32_t rotl32(uint32_t x, uint32_t r) {
  return (x << r) | (x >> (32u - r));
}

__device__ __forceinline__ void threefry2x32(uint32_t k0, uint32_t k1,
                                             uint32_t x0, uint32_t x1,
                                             uint32_t& o0, uint32_t& o1) {
  uint32_t ks0 = k0, ks1 = k1, ks2 = k0 ^ k1 ^ 0x1BD11BDAu;
  x0 += ks0; x1 += ks1;
  x0 += x1; x1 = rotl32(x1, 13); x1 ^= x0;
  x0 += x1; x1 = rotl32(x1, 15); x1 ^= x0;
  x0 += x1; x1 = rotl32(x1, 26); x1 ^= x0;
  x0 += x1; x1 = rotl32(x1, 6);  x1 ^= x0;
  x0 += ks1; x1 += ks2 + 1u;
  x0 += x1; x1 = rotl32(x1, 17); x1 ^= x0;
  x0 += x1; x1 = rotl32(x1, 29); x1 ^= x0;
  x0 += x1; x1 = rotl32(x1, 16); x1 ^= x0;
  x0 += x1; x1 = rotl32(x1, 24); x1 ^= x0;
  x0 += ks2; x1 += ks0 + 2u;
  x0 += x1; x1 = rotl32(x1, 13); x1 ^= x0;
  x0 += x1; x1 = rotl32(x1, 15); x1 ^= x0;
  x0 += x1; x1 = rotl32(x1, 26); x1 ^= x0;
  x0 += x1; x1 = rotl32(x1, 6);  x1 ^= x0;
  x0 += ks0; x1 += ks1 + 3u;
  x0 += x1; x1 = rotl32(x1, 17); x1 ^= x0;
  x0 += x1; x1 = rotl32(x1, 29); x1 ^= x0;
  x0 += x1; x1 = rotl32(x1, 16); x1 ^= x0;
  x0 += x1; x1 = rotl32(x1, 24); x1 ^= x0;
  x0 += ks1; x1 += ks2 + 4u;
  x0 += x1; x1 = rotl32(x1, 13); x1 ^= x0;
  x0 += x1; x1 = rotl32(x1, 15); x1 ^= x0;
  x0 += x1; x1 = rotl32(x1, 26); x1 ^= x0;
  x0 += x1; x1 = rotl32(x1, 6);  x1 ^= x0;
  x0 += ks2; x1 += ks0 + 5u;
  o0 = x0; o1 = x1;
}

__device__ __forceinline__ float jax_gumbel(uint32_t i) {
  uint32_t o0, o1;
  threefry2x32(0u, 777u, 0u, i, o0, o1);
  uint32_t bits = o0 ^ o1;
  uint32_t fb = (bits >> 9) | 0x3F800000u;
  float u = __uint_as_float(fb) - 1.0f;    // [0,1)
  float uu = fmaxf(TINYF, u + TINYF);
  return -logf(-logf(uu));
}

// ---------------- fused pipeline, one launch, 4 grid barriers ----------------
__global__ __launch_bounds__(NTHR, 2) void fused(
    const float* __restrict__ x, const float* __restrict__ sw,
    const float* __restrict__ att, const int* __restrict__ epoch_p,
    float* __restrict__ out, int* __restrict__ bar,
    double* __restrict__ scores, double* __restrict__ ball,
    double* __restrict__ logits, int* __restrict__ perm,
    float* __restrict__ sm_sort) {
  const int tid = threadIdx.x;
  const int lane = tid & 63;
  const int gw = blockIdx.x * (NTHR / 64) + (tid >> 6);   // 0..2047

  // ---- phase 1: scores[i] = x[i].sw ; ball[i] = x[i].wb  (f64, wave per row)
  for (int i = gw; i < N_T; i += NWAVE) {
    double xv0 = (double)x[i * D_T + lane];
    double xv1 = (double)x[i * D_T + 64 + lane];
    double ps = xv0 * (double)sw[lane] + xv1 * (double)sw[64 + lane];
    double pb = xv0 * (double)att[D_T + lane] + xv1 * (double)att[D_T + 64 + lane];
    ps = wsumd(ps);
    pb = wsumd(pb);
    if (lane == 0) { scores[i] = ps; ball[i] = pb; }
  }
  grid_barrier(bar, 0);

  // ---- phase 2: rank each element; if rank<K, perm[rank]=i
  for (int i = gw; i < N_T; i += NWAVE) {
    double si = scores[i];
    int cnt = 0;
#pragma unroll 8
    for (int j = lane; j < N_T; j += 64) {
      double sj = scores[j];
      cnt += ((sj > si) || (sj == si && j < i)) ? 1 : 0;
    }
    cnt = wsumi(cnt);
    if (lane == 0 && cnt < K_T) perm[cnt] = i;
  }
  grid_barrier(bar, 1);

  // ---- phase 3: per-row softmax + gk + stable rank (one wave per row; f = lane, lane+64, lane+128)
  if (gw < RES_T) {
    int r = gw;
    int pr  = perm[r];
    int pd0 = perm[r + lane];
    int pd1 = perm[r + 64 + lane];
    int pd2 = perm[r + 128 + lane];

    double s0 = ball[pd0], s1 = ball[pd1], s2 = ball[pd2];
    double mx = wmaxd(fmax(s0, fmax(s1, s2)));
    double e0 = exp(s0 - mx), e1 = exp(s1 - mx), e2 = exp(s2 - mx);
    double ssum = wsumd(e0 + e1 + e2);

    float xa = x[pr * D_T + lane];        // dims lane
    float xb = x[pr * D_T + 64 + lane];   // dims 64+lane
    const float4* r0 = (const float4*)(x + (size_t)pd0 * D_T);
    const float4* r1 = (const float4*)(x + (size_t)pd1 * D_T);
    const float4* r2 = (const float4*)(x + (size_t)pd2 * D_T);
    double sq0 = 0.0, sq1 = 0.0, sq2 = 0.0;
#pragma unroll 4
    for (int tt = 0; tt < 32; ++tt) {
      float4 v0 = r0[tt], v1 = r1[tt], v2 = r2[tt];
      float src = (tt < 16) ? xa : xb;
      int base = (tt * 4) & 63;
      float u0 = __shfl(src, base);
      float u1 = __shfl(src, base + 1);
      float u2 = __shfl(src, base + 2);
      float u3 = __shfl(src, base + 3);
      float d;
      d = u0 - v0.x; sq0 += (double)d * (double)d;
      d = u1 - v0.y; sq0 += (double)d * (double)d;
      d = u2 - v0.z; sq0 += (double)d * (double)d;
      d = u3 - v0.w; sq0 += (double)d * (double)d;
      d = u0 - v1.x; sq1 += (double)d * (double)d;
      d = u1 - v1.y; sq1 += (double)d * (double)d;
      d = u2 - v1.z; sq1 += (double)d * (double)d;
      d = u3 - v1.w; sq1 += (double)d * (double)d;
      d = u0 - v2.x; sq2 += (double)d * (double)d;
      d = u1 - v2.y; sq2 += (double)d * (double)d;
      d = u2 - v2.z; sq2 += (double)d * (double)d;
      d = u3 - v2.w; sq2 += (double)d * (double)d;
    }
    double g0v = exp(-sqrt(fmax(sq0, 1e-24)) * 0.5) - 1e-5;
    double g1v = exp(-sqrt(fmax(sq1, 1e-24)) * 0.5) - 1e-5;
    double g2v = exp(-sqrt(fmax(sq2, 1e-24)) * 0.5) - 1e-5;

    // stable descending rank among the row's 192 values (f index tie-break)
    int rk0 = 0, rk1 = 0, rk2 = 0;
#pragma unroll 4
    for (int j = 0; j < 64; ++j) {
      double h0 = __shfl(g0v, j), h1 = __shfl(g1v, j), h2 = __shfl(g2v, j);
      rk0 += ((h0 > g0v) || (h0 == g0v && j < lane)) ? 1 : 0;
      rk0 += (h1 > g0v) ? 1 : 0;
      rk0 += (h2 > g0v) ? 1 : 0;
      rk1 += ((h0 > g1v) || (h0 == g1v)) ? 1 : 0;
      rk1 += ((h1 > g1v) || (h1 == g1v && j < lane)) ? 1 : 0;
      rk1 += (h2 > g1v) ? 1 : 0;
      rk2 += ((h0 > g2v) || (h0 == g2v)) ? 1 : 0;
      rk2 += ((h1 > g2v) || (h1 == g2v)) ? 1 : 0;
      rk2 += ((h2 > g2v) || (h2 == g2v && j < lane)) ? 1 : 0;
    }
    size_t rb = (size_t)r * FS_T;
    double inv = 1.0 / ssum;
    out[rb + rk0] = (float)g0v;  sm_sort[rb + rk0] = (float)(e0 * inv);
    out[rb + rk1] = (float)g1v;  sm_sort[rb + rk1] = (float)(e1 * inv);
    out[rb + rk2] = (float)g2v;  sm_sort[rb + rk2] = (float)(e2 * inv);
  }
  grid_barrier(bar, 2);

  // ---- phase 4: logits[c] = sum_r sm_sort[r][c]  (wave per column)
  if (gw < FS_T) {
    int c = gw;
    double s = 0.0;
    for (int j = lane; j < RES_T; j += 64) s += (double)sm_sort[(size_t)j * FS_T + c];
    s = wsumd(s);
    if (lane == 0) logits[c] = s;
  }
  grid_barrier(bar, 3);

  // ---- phase 5: gumbel softmax * gk  (wave per row)
  if (gw < RES_T) {
    int r = gw;
    int i0 = r * FS_T + lane, i1 = i0 + 64, i2 = i0 + 128;
    float gk0 = out[i0], gk1 = out[i1], gk2 = out[i2];
    float gb0 = jax_gumbel((uint32_t)i0);
    float gb1 = jax_gumbel((uint32_t)i1);
    float gb2 = jax_gumbel((uint32_t)i2);
    double l0 = logits[lane], l1 = logits[64 + lane], l2 = logits[128 + lane];

    int ei = epoch_p[0];
    double epoch;
    if (ei >= 0 && ei <= 100000) epoch = (double)ei;
    else {
      float ef = __int_as_float(ei);
      epoch = (ef >= 0.0f && ef <= 100000.0f) ? (double)ef : 50.0;
    }
    double invtau = 0.1 * exp(0.04605170185988091 * epoch);   // 1/tau0

    float z0 = (lane == 0) ? -INFINITY : (float)(((double)gb0 + l0) * invtau);
    float z1 = (float)(((double)gb1 + l1) * invtau);
    float z2 = (float)(((double)gb2 + l2) * invtau);
    float m = wmaxf(fmaxf(z0, fmaxf(z1, z2)));
    float e0 = (lane == 0) ? 0.0f : expf(z0 - m);
    float e1 = expf(z1 - m);
    float e2 = expf(z2 - m);
    float ssum = wsumf(e0 + e1 + e2);
    float invs = 1.0f / ssum;
    out[i0] = gk0 * (e0 * invs);
    out[i1] = gk1 * (e1 * invs);
    out[i2] = gk2 * (e2 * invs);
  }
}

// ---------------- launcher ----------------
extern "C" void kernel_launch(void* const* d_in, const int* in_sizes, int n_in,
                              void* d_out, int out_size, void* d_ws, size_t ws_size,
                              hipStream_t stream) {
  const float* x   = (const float*)d_in[0];
  // d_in[1] = edge_index (unused by the reference)
  const float* sw  = (const float*)d_in[2];
  // d_in[3] = score_b (order-preserving constant shift; unused)
  const float* att = (const float*)d_in[4];
  const int* epoch = (const int*)d_in[5];
  float* out = (float*)d_out;

  char* ws = (char*)d_ws;
  int*    bar     = (int*)ws;                   // 16 ints: cnt[0..3], flag[8..11]
  double* scores  = (double*)(ws + 64);         // 3072
  double* ball    = scores + N_T;               // 3072
  double* logits  = ball + N_T;                 // 192
  int*    perm    = (int*)(logits + FS_T);      // 1536
  float*  sm_sort = (float*)(perm + K_T);       // 258240   (~1.09 MB total)

  hipMemsetAsync(bar, 0, 64, stream);           // reset barrier state every launch
  fused<<<NBLK, NTHR, 0, stream>>>(x, sw, att, epoch, out, bar,
                                   scores, ball, logits, perm, sm_sort);
}

// Round 7
// 118.786 us; speedup vs baseline: 3.7201x; 3.7201x over previous
//
#include <hip/hip_runtime.h>
#include <stdint.h>

#define N_T   3072
#define D_T   128
#define K_T   1536
#define FS_T  192
#define RES_T 1345
#define TOT_T (RES_T * FS_T)   // 258240
#define TINYF 1.17549435e-38f
#define NBLK  256
#define NTHR  512
#define NWAVE 2048             // NBLK * NTHR/64

// ---------------- wave-level reductions (64 lanes, fixed order, deterministic) ----------------

__device__ __forceinline__ double wsumd(double v) {
  v += __shfl_xor(v, 1);  v += __shfl_xor(v, 2);  v += __shfl_xor(v, 4);
  v += __shfl_xor(v, 8);  v += __shfl_xor(v, 16); v += __shfl_xor(v, 32);
  return v;
}
__device__ __forceinline__ double wmaxd(double v) {
  v = fmax(v, __shfl_xor(v, 1));  v = fmax(v, __shfl_xor(v, 2));
  v = fmax(v, __shfl_xor(v, 4));  v = fmax(v, __shfl_xor(v, 8));
  v = fmax(v, __shfl_xor(v, 16)); v = fmax(v, __shfl_xor(v, 32));
  return v;
}
__device__ __forceinline__ float wsumf(float v) {
  v += __shfl_xor(v, 1);  v += __shfl_xor(v, 2);  v += __shfl_xor(v, 4);
  v += __shfl_xor(v, 8);  v += __shfl_xor(v, 16); v += __shfl_xor(v, 32);
  return v;
}
__device__ __forceinline__ float wmaxf(float v) {
  v = fmaxf(v, __shfl_xor(v, 1));  v = fmaxf(v, __shfl_xor(v, 2));
  v = fmaxf(v, __shfl_xor(v, 4));  v = fmaxf(v, __shfl_xor(v, 8));
  v = fmaxf(v, __shfl_xor(v, 16)); v = fmaxf(v, __shfl_xor(v, 32));
  return v;
}
__device__ __forceinline__ int wsumi(int v) {
  v += __shfl_xor(v, 1);  v += __shfl_xor(v, 2);  v += __shfl_xor(v, 4);
  v += __shfl_xor(v, 8);  v += __shfl_xor(v, 16); v += __shfl_xor(v, 32);
  return v;
}

// ---------------- multi-flag grid barrier: no RMW, no shared-line contention ----------------
// flags: int[4][NBLK], zeroed by hipMemsetAsync before each kernel launch.
// Each block release-stores its own word; wave 0 polls all NBLK words (4/lane).
// Safe: 256 blocks <= 256 CUs at this size -> all blocks co-resident.
__device__ __forceinline__ void grid_barrier(int* flags, int b) {
  __syncthreads();                               // all waves of this block done with the phase
  int* f = flags + b * NBLK;
  if (threadIdx.x < 64) {
    int lane = threadIdx.x;
    if (lane == 0) {
      __threadfence();                           // make this block's writes agent-visible
      __hip_atomic_store(&f[blockIdx.x], 1, __ATOMIC_RELEASE, __HIP_MEMORY_SCOPE_AGENT);
    }
    for (;;) {
      int v0 = __hip_atomic_load(&f[lane],       __ATOMIC_RELAXED, __HIP_MEMORY_SCOPE_AGENT);
      int v1 = __hip_atomic_load(&f[lane + 64],  __ATOMIC_RELAXED, __HIP_MEMORY_SCOPE_AGENT);
      int v2 = __hip_atomic_load(&f[lane + 128], __ATOMIC_RELAXED, __HIP_MEMORY_SCOPE_AGENT);
      int v3 = __hip_atomic_load(&f[lane + 192], __ATOMIC_RELAXED, __HIP_MEMORY_SCOPE_AGENT);
      if (__all((v0 & v1 & v2 & v3) != 0)) break;
      __builtin_amdgcn_s_sleep(1);
    }
    __threadfence();                             // acquire side: order polled flag before later reads
  }
  __syncthreads();                               // release the other waves
}

// ---------------- threefry-2x32 (exact JAX bits, partitionable layout) ----------------

__device__ __forceinline__ uint32_t rotl32(uint32_t x, uint32_t r) {
  return (x << r) | (x >> (32u - r));
}

__device__ __forceinline__ void threefry2x32(uint32_t k0, uint32_t k1,
                                             uint32_t x0, uint32_t x1,
                                             uint32_t& o0, uint32_t& o1) {
  uint32_t ks0 = k0, ks1 = k1, ks2 = k0 ^ k1 ^ 0x1BD11BDAu;
  x0 += ks0; x1 += ks1;
  x0 += x1; x1 = rotl32(x1, 13); x1 ^= x0;
  x0 += x1; x1 = rotl32(x1, 15); x1 ^= x0;
  x0 += x1; x1 = rotl32(x1, 26); x1 ^= x0;
  x0 += x1; x1 = rotl32(x1, 6);  x1 ^= x0;
  x0 += ks1; x1 += ks2 + 1u;
  x0 += x1; x1 = rotl32(x1, 17); x1 ^= x0;
  x0 += x1; x1 = rotl32(x1, 29); x1 ^= x0;
  x0 += x1; x1 = rotl32(x1, 16); x1 ^= x0;
  x0 += x1; x1 = rotl32(x1, 24); x1 ^= x0;
  x0 += ks2; x1 += ks0 + 2u;
  x0 += x1; x1 = rotl32(x1, 13); x1 ^= x0;
  x0 += x1; x1 = rotl32(x1, 15); x1 ^= x0;
  x0 += x1; x1 = rotl32(x1, 26); x1 ^= x0;
  x0 += x1; x1 = rotl32(x1, 6);  x1 ^= x0;
  x0 += ks0; x1 += ks1 + 3u;
  x0 += x1; x1 = rotl32(x1, 17); x1 ^= x0;
  x0 += x1; x1 = rotl32(x1, 29); x1 ^= x0;
  x0 += x1; x1 = rotl32(x1, 16); x1 ^= x0;
  x0 += x1; x1 = rotl32(x1, 24); x1 ^= x0;
  x0 += ks1; x1 += ks2 + 4u;
  x0 += x1; x1 = rotl32(x1, 13); x1 ^= x0;
  x0 += x1; x1 = rotl32(x1, 15); x1 ^= x0;
  x0 += x1; x1 = rotl32(x1, 26); x1 ^= x0;
  x0 += x1; x1 = rotl32(x1, 6);  x1 ^= x0;
  x0 += ks2; x1 += ks0 + 5u;
  o0 = x0; o1 = x1;
}

__device__ __forceinline__ float jax_gumbel(uint32_t i) {
  uint32_t o0, o1;
  threefry2x32(0u, 777u, 0u, i, o0, o1);
  uint32_t bits = o0 ^ o1;
  uint32_t fb = (bits >> 9) | 0x3F800000u;
  float u = __uint_as_float(fb) - 1.0f;    // [0,1)
  float uu = fmaxf(TINYF, u + TINYF);
  return -logf(-logf(uu));
}

// ---------------- fused pipeline, one launch, 4 grid barriers ----------------
__global__ __launch_bounds__(NTHR, 2) void fused(
    const float* __restrict__ x, const float* __restrict__ sw,
    const float* __restrict__ att, const int* __restrict__ epoch_p,
    float* __restrict__ out, int* __restrict__ flags,
    double* __restrict__ scores, double* __restrict__ ball,
    double* __restrict__ logits, int* __restrict__ perm,
    float* __restrict__ sm_sort) {
  const int tid = threadIdx.x;
  const int lane = tid & 63;
  const int gw = blockIdx.x * (NTHR / 64) + (tid >> 6);   // 0..2047

  // ---- phase 1: scores[i] = x[i].sw ; ball[i] = x[i].wb  (f64, wave per row)
  for (int i = gw; i < N_T; i += NWAVE) {
    double xv0 = (double)x[i * D_T + lane];
    double xv1 = (double)x[i * D_T + 64 + lane];
    double ps = xv0 * (double)sw[lane] + xv1 * (double)sw[64 + lane];
    double pb = xv0 * (double)att[D_T + lane] + xv1 * (double)att[D_T + 64 + lane];
    ps = wsumd(ps);
    pb = wsumd(pb);
    if (lane == 0) { scores[i] = ps; ball[i] = pb; }
  }
  grid_barrier(flags, 0);

  // ---- phase 2: rank each element; if rank<K, perm[rank]=i
  for (int i = gw; i < N_T; i += NWAVE) {
    double si = scores[i];
    int cnt = 0;
#pragma unroll 8
    for (int j = lane; j < N_T; j += 64) {
      double sj = scores[j];
      cnt += ((sj > si) || (sj == si && j < i)) ? 1 : 0;
    }
    cnt = wsumi(cnt);
    if (lane == 0 && cnt < K_T) perm[cnt] = i;
  }
  grid_barrier(flags, 1);

  // ---- phase 3: per-row softmax + gk + stable rank (one wave per row; f = lane, lane+64, lane+128)
  if (gw < RES_T) {
    int r = gw;
    int pr  = perm[r];
    int pd0 = perm[r + lane];
    int pd1 = perm[r + 64 + lane];
    int pd2 = perm[r + 128 + lane];

    double s0 = ball[pd0], s1 = ball[pd1], s2 = ball[pd2];
    double mx = wmaxd(fmax(s0, fmax(s1, s2)));
    double e0 = exp(s0 - mx), e1 = exp(s1 - mx), e2 = exp(s2 - mx);
    double ssum = wsumd(e0 + e1 + e2);

    float xa = x[pr * D_T + lane];        // dims lane
    float xb = x[pr * D_T + 64 + lane];   // dims 64+lane
    const float4* r0 = (const float4*)(x + (size_t)pd0 * D_T);
    const float4* r1 = (const float4*)(x + (size_t)pd1 * D_T);
    const float4* r2 = (const float4*)(x + (size_t)pd2 * D_T);
    double sq0 = 0.0, sq1 = 0.0, sq2 = 0.0;
#pragma unroll 4
    for (int tt = 0; tt < 32; ++tt) {
      float4 v0 = r0[tt], v1 = r1[tt], v2 = r2[tt];
      float src = (tt < 16) ? xa : xb;
      int base = (tt * 4) & 63;
      float u0 = __shfl(src, base);
      float u1 = __shfl(src, base + 1);
      float u2 = __shfl(src, base + 2);
      float u3 = __shfl(src, base + 3);
      float d;
      d = u0 - v0.x; sq0 += (double)d * (double)d;
      d = u1 - v0.y; sq0 += (double)d * (double)d;
      d = u2 - v0.z; sq0 += (double)d * (double)d;
      d = u3 - v0.w; sq0 += (double)d * (double)d;
      d = u0 - v1.x; sq1 += (double)d * (double)d;
      d = u1 - v1.y; sq1 += (double)d * (double)d;
      d = u2 - v1.z; sq1 += (double)d * (double)d;
      d = u3 - v1.w; sq1 += (double)d * (double)d;
      d = u0 - v2.x; sq2 += (double)d * (double)d;
      d = u1 - v2.y; sq2 += (double)d * (double)d;
      d = u2 - v2.z; sq2 += (double)d * (double)d;
      d = u3 - v2.w; sq2 += (double)d * (double)d;
    }
    double g0v = exp(-sqrt(fmax(sq0, 1e-24)) * 0.5) - 1e-5;
    double g1v = exp(-sqrt(fmax(sq1, 1e-24)) * 0.5) - 1e-5;
    double g2v = exp(-sqrt(fmax(sq2, 1e-24)) * 0.5) - 1e-5;

    // stable descending rank among the row's 192 values (f index tie-break)
    int rk0 = 0, rk1 = 0, rk2 = 0;
#pragma unroll 4
    for (int j = 0; j < 64; ++j) {
      double h0 = __shfl(g0v, j), h1 = __shfl(g1v, j), h2 = __shfl(g2v, j);
      rk0 += ((h0 > g0v) || (h0 == g0v && j < lane)) ? 1 : 0;
      rk0 += (h1 > g0v) ? 1 : 0;
      rk0 += (h2 > g0v) ? 1 : 0;
      rk1 += ((h0 > g1v) || (h0 == g1v)) ? 1 : 0;
      rk1 += ((h1 > g1v) || (h1 == g1v && j < lane)) ? 1 : 0;
      rk1 += (h2 > g1v) ? 1 : 0;
      rk2 += ((h0 > g2v) || (h0 == g2v)) ? 1 : 0;
      rk2 += ((h1 > g2v) || (h1 == g2v)) ? 1 : 0;
      rk2 += ((h2 > g2v) || (h2 == g2v && j < lane)) ? 1 : 0;
    }
    size_t rb = (size_t)r * FS_T;
    double inv = 1.0 / ssum;
    out[rb + rk0] = (float)g0v;  sm_sort[rb + rk0] = (float)(e0 * inv);
    out[rb + rk1] = (float)g1v;  sm_sort[rb + rk1] = (float)(e1 * inv);
    out[rb + rk2] = (float)g2v;  sm_sort[rb + rk2] = (float)(e2 * inv);
  }
  grid_barrier(flags, 2);

  // ---- phase 4: logits[c] = sum_r sm_sort[r][c]  (wave per column)
  if (gw < FS_T) {
    int c = gw;
    double s = 0.0;
    for (int j = lane; j < RES_T; j += 64) s += (double)sm_sort[(size_t)j * FS_T + c];
    s = wsumd(s);
    if (lane == 0) logits[c] = s;
  }
  grid_barrier(flags, 3);

  // ---- phase 5: gumbel softmax * gk  (wave per row)
  if (gw < RES_T) {
    int r = gw;
    int i0 = r * FS_T + lane, i1 = i0 + 64, i2 = i0 + 128;
    float gk0 = out[i0], gk1 = out[i1], gk2 = out[i2];
    float gb0 = jax_gumbel((uint32_t)i0);
    float gb1 = jax_gumbel((uint32_t)i1);
    float gb2 = jax_gumbel((uint32_t)i2);
    double l0 = logits[lane], l1 = logits[64 + lane], l2 = logits[128 + lane];

    int ei = epoch_p[0];
    double epoch;
    if (ei >= 0 && ei <= 100000) epoch = (double)ei;
    else {
      float ef = __int_as_float(ei);
      epoch = (ef >= 0.0f && ef <= 100000.0f) ? (double)ef : 50.0;
    }
    double invtau = 0.1 * exp(0.04605170185988091 * epoch);   // 1/tau0

    float z0 = (lane == 0) ? -INFINITY : (float)(((double)gb0 + l0) * invtau);
    float z1 = (float)(((double)gb1 + l1) * invtau);
    float z2 = (float)(((double)gb2 + l2) * invtau);
    float m = wmaxf(fmaxf(z0, fmaxf(z1, z2)));
    float e0 = (lane == 0) ? 0.0f : expf(z0 - m);
    float e1 = expf(z1 - m);
    float e2 = expf(z2 - m);
    float ssum = wsumf(e0 + e1 + e2);
    float invs = 1.0f / ssum;
    out[i0] = gk0 * (e0 * invs);
    out[i1] = gk1 * (e1 * invs);
    out[i2] = gk2 * (e2 * invs);
  }
}

// ---------------- launcher ----------------
extern "C" void kernel_launch(void* const* d_in, const int* in_sizes, int n_in,
                              void* d_out, int out_size, void* d_ws, size_t ws_size,
                              hipStream_t stream) {
  const float* x   = (const float*)d_in[0];
  // d_in[1] = edge_index (unused by the reference)
  const float* sw  = (const float*)d_in[2];
  // d_in[3] = score_b (order-preserving constant shift; unused)
  const float* att = (const float*)d_in[4];
  const int* epoch = (const int*)d_in[5];
  float* out = (float*)d_out;

  char* ws = (char*)d_ws;
  int*    flags   = (int*)ws;                   // 4 barriers x 256 block-flags = 4 KB
  double* scores  = (double*)(ws + 4096);       // 3072
  double* ball    = scores + N_T;               // 3072
  double* logits  = ball + N_T;                 // 192
  int*    perm    = (int*)(logits + FS_T);      // 1536
  float*  sm_sort = (float*)(perm + K_T);       // 258240   (~1.09 MB total)

  (void)hipMemsetAsync(flags, 0, 4096, stream); // reset barrier flags every launch
  fused<<<NBLK, NTHR, 0, stream>>>(x, sw, att, epoch, out, flags,
                                   scores, ball, logits, perm, sm_sort);
}

// Round 8
// 105.936 us; speedup vs baseline: 4.1714x; 1.1213x over previous
//
#include <hip/hip_runtime.h>
#include <stdint.h>

#define N_T   3072
#define D_T   128
#define K_T   1536
#define FS_T  192
#define RES_T 1345
#define TOT_T (RES_T * FS_T)   // 258240
#define TINYF 1.17549435e-38f
#define NBLK  256
#define NTHR  512
#define NWAVE 2048             // NBLK * NTHR/64

// ---------------- wave-level reductions (64 lanes, fixed order, deterministic) ----------------

__device__ __forceinline__ double wsumd(double v) {
  v += __shfl_xor(v, 1);  v += __shfl_xor(v, 2);  v += __shfl_xor(v, 4);
  v += __shfl_xor(v, 8);  v += __shfl_xor(v, 16); v += __shfl_xor(v, 32);
  return v;
}
__device__ __forceinline__ double wmaxd(double v) {
  v = fmax(v, __shfl_xor(v, 1));  v = fmax(v, __shfl_xor(v, 2));
  v = fmax(v, __shfl_xor(v, 4));  v = fmax(v, __shfl_xor(v, 8));
  v = fmax(v, __shfl_xor(v, 16)); v = fmax(v, __shfl_xor(v, 32));
  return v;
}
__device__ __forceinline__ float wsumf(float v) {
  v += __shfl_xor(v, 1);  v += __shfl_xor(v, 2);  v += __shfl_xor(v, 4);
  v += __shfl_xor(v, 8);  v += __shfl_xor(v, 16); v += __shfl_xor(v, 32);
  return v;
}
__device__ __forceinline__ float wmaxf(float v) {
  v = fmaxf(v, __shfl_xor(v, 1));  v = fmaxf(v, __shfl_xor(v, 2));
  v = fmaxf(v, __shfl_xor(v, 4));  v = fmaxf(v, __shfl_xor(v, 8));
  v = fmaxf(v, __shfl_xor(v, 16)); v = fmaxf(v, __shfl_xor(v, 32));
  return v;
}
__device__ __forceinline__ int wsumi(int v) {
  v += __shfl_xor(v, 1);  v += __shfl_xor(v, 2);  v += __shfl_xor(v, 4);
  v += __shfl_xor(v, 8);  v += __shfl_xor(v, 16); v += __shfl_xor(v, 32);
  return v;
}

// ---------------- hierarchical grid barrier: arrive-flags -> block0 aggregates -> done word ----
// sync layout (zeroed per launch): arrive[4][NBLK] at 0..4095; done[b] at 4096 + b*128 bytes.
// One poller (block 0 wave 0) reads the 256 arrival words; all other blocks poll a single
// 'done' word with ONE thread at a slow cadence -> no LLC line congestion.
// Safe: 256 blocks, 1 per CU -> all co-resident.
__device__ __forceinline__ void grid_barrier(int* sync, int b) {
  __syncthreads();                               // all waves of this block done with the phase
  int* arrive = sync + b * NBLK;
  int* done   = sync + 4 * NBLK + b * 32;        // 128-byte-separated word
  if (threadIdx.x == 0) {
    __threadfence();                             // release: make this block's writes agent-visible
    __hip_atomic_store(&arrive[blockIdx.x], 1, __ATOMIC_RELEASE, __HIP_MEMORY_SCOPE_AGENT);
  }
  if (blockIdx.x == 0) {
    if (threadIdx.x < 64) {
      int lane = threadIdx.x;
      for (;;) {
        int v0 = __hip_atomic_load(&arrive[lane],       __ATOMIC_RELAXED, __HIP_MEMORY_SCOPE_AGENT);
        int v1 = __hip_atomic_load(&arrive[lane + 64],  __ATOMIC_RELAXED, __HIP_MEMORY_SCOPE_AGENT);
        int v2 = __hip_atomic_load(&arrive[lane + 128], __ATOMIC_RELAXED, __HIP_MEMORY_SCOPE_AGENT);
        int v3 = __hip_atomic_load(&arrive[lane + 192], __ATOMIC_RELAXED, __HIP_MEMORY_SCOPE_AGENT);
        if (__all((v0 & v1 & v2 & v3) != 0)) break;
        __builtin_amdgcn_s_sleep(2);
      }
      if (lane == 0) {
        __threadfence();
        __hip_atomic_store(done, 1, __ATOMIC_RELEASE, __HIP_MEMORY_SCOPE_AGENT);
      }
    }
  } else {
    if (threadIdx.x == 0) {
      while (__hip_atomic_load(done, __ATOMIC_RELAXED, __HIP_MEMORY_SCOPE_AGENT) == 0) {
        __builtin_amdgcn_s_sleep(8);
      }
    }
  }
  if (threadIdx.x == 0) __threadfence();         // acquire: no stale cached data after barrier
  __syncthreads();                               // release the other waves
}

// ---------------- threefry-2x32 (exact JAX bits, partitionable layout) ----------------

__device__ __forceinline__ uint32_t rotl32(uint32_t x, uint32_t r) {
  return (x << r) | (x >> (32u - r));
}

__device__ __forceinline__ void threefry2x32(uint32_t k0, uint32_t k1,
                                             uint32_t x0, uint32_t x1,
                                             uint32_t& o0, uint32_t& o1) {
  uint32_t ks0 = k0, ks1 = k1, ks2 = k0 ^ k1 ^ 0x1BD11BDAu;
  x0 += ks0; x1 += ks1;
  x0 += x1; x1 = rotl32(x1, 13); x1 ^= x0;
  x0 += x1; x1 = rotl32(x1, 15); x1 ^= x0;
  x0 += x1; x1 = rotl32(x1, 26); x1 ^= x0;
  x0 += x1; x1 = rotl32(x1, 6);  x1 ^= x0;
  x0 += ks1; x1 += ks2 + 1u;
  x0 += x1; x1 = rotl32(x1, 17); x1 ^= x0;
  x0 += x1; x1 = rotl32(x1, 29); x1 ^= x0;
  x0 += x1; x1 = rotl32(x1, 16); x1 ^= x0;
  x0 += x1; x1 = rotl32(x1, 24); x1 ^= x0;
  x0 += ks2; x1 += ks0 + 2u;
  x0 += x1; x1 = rotl32(x1, 13); x1 ^= x0;
  x0 += x1; x1 = rotl32(x1, 15); x1 ^= x0;
  x0 += x1; x1 = rotl32(x1, 26); x1 ^= x0;
  x0 += x1; x1 = rotl32(x1, 6);  x1 ^= x0;
  x0 += ks0; x1 += ks1 + 3u;
  x0 += x1; x1 = rotl32(x1, 17); x1 ^= x0;
  x0 += x1; x1 = rotl32(x1, 29); x1 ^= x0;
  x0 += x1; x1 = rotl32(x1, 16); x1 ^= x0;
  x0 += x1; x1 = rotl32(x1, 24); x1 ^= x0;
  x0 += ks1; x1 += ks2 + 4u;
  x0 += x1; x1 = rotl32(x1, 13); x1 ^= x0;
  x0 += x1; x1 = rotl32(x1, 15); x1 ^= x0;
  x0 += x1; x1 = rotl32(x1, 26); x1 ^= x0;
  x0 += x1; x1 = rotl32(x1, 6);  x1 ^= x0;
  x0 += ks2; x1 += ks0 + 5u;
  o0 = x0; o1 = x1;
}

__device__ __forceinline__ float jax_gumbel(uint32_t i) {
  uint32_t o0, o1;
  threefry2x32(0u, 777u, 0u, i, o0, o1);
  uint32_t bits = o0 ^ o1;
  uint32_t fb = (bits >> 9) | 0x3F800000u;
  float u = __uint_as_float(fb) - 1.0f;    // [0,1)
  float uu = fmaxf(TINYF, u + TINYF);
  return -logf(-logf(uu));
}

// ---------------- fused pipeline, one launch, 4 grid barriers ----------------
__global__ __launch_bounds__(NTHR, 2) void fused(
    const float* __restrict__ x, const float* __restrict__ sw,
    const float* __restrict__ att, const int* __restrict__ epoch_p,
    float* __restrict__ out, int* __restrict__ sync,
    double* __restrict__ scores, double* __restrict__ ball,
    double* __restrict__ logits, int* __restrict__ perm,
    float* __restrict__ sm_sort) {
  const int tid = threadIdx.x;
  const int lane = tid & 63;
  const int gw = blockIdx.x * (NTHR / 64) + (tid >> 6);   // 0..2047

  // ---- phase 1: scores[i] = x[i].sw ; ball[i] = x[i].wb  (f64, wave per row)
  for (int i = gw; i < N_T; i += NWAVE) {
    double xv0 = (double)x[i * D_T + lane];
    double xv1 = (double)x[i * D_T + 64 + lane];
    double ps = xv0 * (double)sw[lane] + xv1 * (double)sw[64 + lane];
    double pb = xv0 * (double)att[D_T + lane] + xv1 * (double)att[D_T + 64 + lane];
    ps = wsumd(ps);
    pb = wsumd(pb);
    if (lane == 0) { scores[i] = ps; ball[i] = pb; }
  }
  grid_barrier(sync, 0);

  // ---- phase 2: rank each element; if rank<K, perm[rank]=i
  for (int i = gw; i < N_T; i += NWAVE) {
    double si = scores[i];
    int cnt = 0;
#pragma unroll 8
    for (int j = lane; j < N_T; j += 64) {
      double sj = scores[j];
      cnt += ((sj > si) || (sj == si && j < i)) ? 1 : 0;
    }
    cnt = wsumi(cnt);
    if (lane == 0 && cnt < K_T) perm[cnt] = i;
  }
  grid_barrier(sync, 1);

  // ---- phase 3: per-row softmax + gk + stable rank (one wave per row; f = lane, lane+64, lane+128)
  if (gw < RES_T) {
    int r = gw;
    int pr  = perm[r];
    int pd0 = perm[r + lane];
    int pd1 = perm[r + 64 + lane];
    int pd2 = perm[r + 128 + lane];

    double s0 = ball[pd0], s1 = ball[pd1], s2 = ball[pd2];
    double mx = wmaxd(fmax(s0, fmax(s1, s2)));
    double e0 = exp(s0 - mx), e1 = exp(s1 - mx), e2 = exp(s2 - mx);
    double ssum = wsumd(e0 + e1 + e2);

    float xa = x[pr * D_T + lane];        // dims lane
    float xb = x[pr * D_T + 64 + lane];   // dims 64+lane
    const float4* r0 = (const float4*)(x + (size_t)pd0 * D_T);
    const float4* r1 = (const float4*)(x + (size_t)pd1 * D_T);
    const float4* r2 = (const float4*)(x + (size_t)pd2 * D_T);
    double sq0 = 0.0, sq1 = 0.0, sq2 = 0.0;
#pragma unroll 4
    for (int tt = 0; tt < 32; ++tt) {
      float4 v0 = r0[tt], v1 = r1[tt], v2 = r2[tt];
      float src = (tt < 16) ? xa : xb;
      int base = (tt * 4) & 63;
      float u0 = __shfl(src, base);
      float u1 = __shfl(src, base + 1);
      float u2 = __shfl(src, base + 2);
      float u3 = __shfl(src, base + 3);
      float d;
      d = u0 - v0.x; sq0 += (double)d * (double)d;
      d = u1 - v0.y; sq0 += (double)d * (double)d;
      d = u2 - v0.z; sq0 += (double)d * (double)d;
      d = u3 - v0.w; sq0 += (double)d * (double)d;
      d = u0 - v1.x; sq1 += (double)d * (double)d;
      d = u1 - v1.y; sq1 += (double)d * (double)d;
      d = u2 - v1.z; sq1 += (double)d * (double)d;
      d = u3 - v1.w; sq1 += (double)d * (double)d;
      d = u0 - v2.x; sq2 += (double)d * (double)d;
      d = u1 - v2.y; sq2 += (double)d * (double)d;
      d = u2 - v2.z; sq2 += (double)d * (double)d;
      d = u3 - v2.w; sq2 += (double)d * (double)d;
    }
    double g0v = exp(-sqrt(fmax(sq0, 1e-24)) * 0.5) - 1e-5;
    double g1v = exp(-sqrt(fmax(sq1, 1e-24)) * 0.5) - 1e-5;
    double g2v = exp(-sqrt(fmax(sq2, 1e-24)) * 0.5) - 1e-5;

    // stable descending rank among the row's 192 values (f index tie-break)
    int rk0 = 0, rk1 = 0, rk2 = 0;
#pragma unroll 4
    for (int j = 0; j < 64; ++j) {
      double h0 = __shfl(g0v, j), h1 = __shfl(g1v, j), h2 = __shfl(g2v, j);
      rk0 += ((h0 > g0v) || (h0 == g0v && j < lane)) ? 1 : 0;
      rk0 += (h1 > g0v) ? 1 : 0;
      rk0 += (h2 > g0v) ? 1 : 0;
      rk1 += ((h0 > g1v) || (h0 == g1v)) ? 1 : 0;
      rk1 += ((h1 > g1v) || (h1 == g1v && j < lane)) ? 1 : 0;
      rk1 += (h2 > g1v) ? 1 : 0;
      rk2 += ((h0 > g2v) || (h0 == g2v)) ? 1 : 0;
      rk2 += ((h1 > g2v) || (h1 == g2v)) ? 1 : 0;
      rk2 += ((h2 > g2v) || (h2 == g2v && j < lane)) ? 1 : 0;
    }
    size_t rb = (size_t)r * FS_T;
    double inv = 1.0 / ssum;
    out[rb + rk0] = (float)g0v;  sm_sort[rb + rk0] = (float)(e0 * inv);
    out[rb + rk1] = (float)g1v;  sm_sort[rb + rk1] = (float)(e1 * inv);
    out[rb + rk2] = (float)g2v;  sm_sort[rb + rk2] = (float)(e2 * inv);
  }
  grid_barrier(sync, 2);

  // ---- phase 4: logits[c] = sum_r sm_sort[r][c]  (wave per column)
  if (gw < FS_T) {
    int c = gw;
    double s = 0.0;
    for (int j = lane; j < RES_T; j += 64) s += (double)sm_sort[(size_t)j * FS_T + c];
    s = wsumd(s);
    if (lane == 0) logits[c] = s;
  }
  grid_barrier(sync, 3);

  // ---- phase 5: gumbel softmax * gk  (wave per row)
  if (gw < RES_T) {
    int r = gw;
    int i0 = r * FS_T + lane, i1 = i0 + 64, i2 = i0 + 128;
    float gk0 = out[i0], gk1 = out[i1], gk2 = out[i2];
    float gb0 = jax_gumbel((uint32_t)i0);
    float gb1 = jax_gumbel((uint32_t)i1);
    float gb2 = jax_gumbel((uint32_t)i2);
    double l0 = logits[lane], l1 = logits[64 + lane], l2 = logits[128 + lane];

    int ei = epoch_p[0];
    double epoch;
    if (ei >= 0 && ei <= 100000) epoch = (double)ei;
    else {
      float ef = __int_as_float(ei);
      epoch = (ef >= 0.0f && ef <= 100000.0f) ? (double)ef : 50.0;
    }
    double invtau = 0.1 * exp(0.04605170185988091 * epoch);   // 1/tau0

    float z0 = (lane == 0) ? -INFINITY : (float)(((double)gb0 + l0) * invtau);
    float z1 = (float)(((double)gb1 + l1) * invtau);
    float z2 = (float)(((double)gb2 + l2) * invtau);
    float m = wmaxf(fmaxf(z0, fmaxf(z1, z2)));
    float e0 = (lane == 0) ? 0.0f : expf(z0 - m);
    float e1 = expf(z1 - m);
    float e2 = expf(z2 - m);
    float ssum = wsumf(e0 + e1 + e2);
    float invs = 1.0f / ssum;
    out[i0] = gk0 * (e0 * invs);
    out[i1] = gk1 * (e1 * invs);
    out[i2] = gk2 * (e2 * invs);
  }
}

// ---------------- launcher ----------------
extern "C" void kernel_launch(void* const* d_in, const int* in_sizes, int n_in,
                              void* d_out, int out_size, void* d_ws, size_t ws_size,
                              hipStream_t stream) {
  const float* x   = (const float*)d_in[0];
  // d_in[1] = edge_index (unused by the reference)
  const float* sw  = (const float*)d_in[2];
  // d_in[3] = score_b (order-preserving constant shift; unused)
  const float* att = (const float*)d_in[4];
  const int* epoch = (const int*)d_in[5];
  float* out = (float*)d_out;

  char* ws = (char*)d_ws;
  int*    sync    = (int*)ws;                   // arrive[4][256] + done words: < 8 KB
  double* scores  = (double*)(ws + 8192);       // 3072
  double* ball    = scores + N_T;               // 3072
  double* logits  = ball + N_T;                 // 192
  int*    perm    = (int*)(logits + FS_T);      // 1536
  float*  sm_sort = (float*)(perm + K_T);       // 258240   (~1.1 MB total)

  (void)hipMemsetAsync(sync, 0, 8192, stream);  // reset barrier state every launch
  fused<<<NBLK, NTHR, 0, stream>>>(x, sw, att, epoch, out, sync,
                                   scores, ball, logits, perm, sm_sort);
}

// Round 9
// 64.116 us; speedup vs baseline: 6.8921x; 1.6523x over previous
//
#include <hip/hip_runtime.h>
#include <stdint.h>

#define N_T   3072
#define D_T   128
#define K_T   1536
#define FS_T  192
#define RES_T 1345
#define TOT_T (RES_T * FS_T)   // 258240
#define TINYF 1.17549435e-38f
#define NBLK  256
#define NTHR  384
#define WPB   6                // waves per block
#define NWAVE (NBLK * WPB)     // 1536

// ---------------- relaxed agent-scope (LLC write-through) accessors ----------------
// On gfx950, AGENT-scope atomics execute at the LLC, bypassing the non-coherent
// per-XCD L1/L2 (verified mechanism: learn_hip m20 cross-XCD atomics). Used for all
// cross-phase data so no cache-flushing fences are ever needed.
__device__ __forceinline__ void ast_d(double* p, double v) { __hip_atomic_store(p, v, __ATOMIC_RELAXED, __HIP_MEMORY_SCOPE_AGENT); }
__device__ __forceinline__ void ast_f(float* p, float v)   { __hip_atomic_store(p, v, __ATOMIC_RELAXED, __HIP_MEMORY_SCOPE_AGENT); }
__device__ __forceinline__ void ast_i(int* p, int v)       { __hip_atomic_store(p, v, __ATOMIC_RELAXED, __HIP_MEMORY_SCOPE_AGENT); }
__device__ __forceinline__ double ald_d(double* p) { return __hip_atomic_load(p, __ATOMIC_RELAXED, __HIP_MEMORY_SCOPE_AGENT); }
__device__ __forceinline__ float  ald_f(float* p)  { return __hip_atomic_load(p, __ATOMIC_RELAXED, __HIP_MEMORY_SCOPE_AGENT); }
__device__ __forceinline__ int    ald_i(int* p)    { return __hip_atomic_load(p, __ATOMIC_RELAXED, __HIP_MEMORY_SCOPE_AGENT); }

// ---------------- wave-level reductions (64 lanes, fixed order, deterministic) ----------------

__device__ __forceinline__ double wsumd(double v) {
  v += __shfl_xor(v, 1);  v += __shfl_xor(v, 2);  v += __shfl_xor(v, 4);
  v += __shfl_xor(v, 8);  v += __shfl_xor(v, 16); v += __shfl_xor(v, 32);
  return v;
}
__device__ __forceinline__ double wmaxd(double v) {
  v = fmax(v, __shfl_xor(v, 1));  v = fmax(v, __shfl_xor(v, 2));
  v = fmax(v, __shfl_xor(v, 4));  v = fmax(v, __shfl_xor(v, 8));
  v = fmax(v, __shfl_xor(v, 16)); v = fmax(v, __shfl_xor(v, 32));
  return v;
}
__device__ __forceinline__ float wsumf(float v) {
  v += __shfl_xor(v, 1);  v += __shfl_xor(v, 2);  v += __shfl_xor(v, 4);
  v += __shfl_xor(v, 8);  v += __shfl_xor(v, 16); v += __shfl_xor(v, 32);
  return v;
}
__device__ __forceinline__ float wmaxf(float v) {
  v = fmaxf(v, __shfl_xor(v, 1));  v = fmaxf(v, __shfl_xor(v, 2));
  v = fmaxf(v, __shfl_xor(v, 4));  v = fmaxf(v, __shfl_xor(v, 8));
  v = fmaxf(v, __shfl_xor(v, 16)); v = fmaxf(v, __shfl_xor(v, 32));
  return v;
}
__device__ __forceinline__ int wsumi(int v) {
  v += __shfl_xor(v, 1);  v += __shfl_xor(v, 2);  v += __shfl_xor(v, 4);
  v += __shfl_xor(v, 8);  v += __shfl_xor(v, 16); v += __shfl_xor(v, 32);
  return v;
}

// ---------------- fence-free hierarchical grid barrier ----------------
// Protocol: every wave drains its (LLC-write-through) stores with vmcnt(0),
// block-syncthreads, then one flag store per block; block 0 aggregates the 256
// arrival words and broadcasts a single done word. NO __threadfence anywhere ->
// no L2 writeback/invalidate; read-only inputs stay cached.
// Safe: 256 blocks <= 256 CUs -> all co-resident.
__device__ __forceinline__ void grid_barrier(int* sync, int b) {
  asm volatile("s_waitcnt vmcnt(0)" ::: "memory");   // my stores are LLC-complete
  __syncthreads();                                   // all waves of block drained
  int* arrive = sync + b * NBLK;
  int* done   = sync + 4 * NBLK + b * 32;            // own 128B line per barrier
  if (blockIdx.x == 0) {
    if (threadIdx.x < 64) {
      int lane = threadIdx.x;
      if (lane == 0) ast_i(&arrive[0], 1);
      for (;;) {
        int v0 = ald_i(&arrive[lane]);
        int v1 = ald_i(&arrive[lane + 64]);
        int v2 = ald_i(&arrive[lane + 128]);
        int v3 = ald_i(&arrive[lane + 192]);
        if (__all((v0 & v1 & v2 & v3) != 0)) break;
        __builtin_amdgcn_s_sleep(1);
      }
      if (lane == 0) ast_i(done, 1);
    }
  } else {
    if (threadIdx.x == 0) {
      ast_i(&arrive[blockIdx.x], 1);
      while (ald_i(done) == 0) __builtin_amdgcn_s_sleep(4);
    }
  }
  asm volatile("" ::: "memory");                     // no reordering across the poll
  __syncthreads();                                   // release the other waves
}

// ---------------- threefry-2x32 (exact JAX bits, partitionable layout) ----------------

__device__ __forceinline__ uint32_t rotl32(uint32_t x, uint32_t r) {
  return (x << r) | (x >> (32u - r));
}

__device__ __forceinline__ void threefry2x32(uint32_t k0, uint32_t k1,
                                             uint32_t x0, uint32_t x1,
                                             uint32_t& o0, uint32_t& o1) {
  uint32_t ks0 = k0, ks1 = k1, ks2 = k0 ^ k1 ^ 0x1BD11BDAu;
  x0 += ks0; x1 += ks1;
  x0 += x1; x1 = rotl32(x1, 13); x1 ^= x0;
  x0 += x1; x1 = rotl32(x1, 15); x1 ^= x0;
  x0 += x1; x1 = rotl32(x1, 26); x1 ^= x0;
  x0 += x1; x1 = rotl32(x1, 6);  x1 ^= x0;
  x0 += ks1; x1 += ks2 + 1u;
  x0 += x1; x1 = rotl32(x1, 17); x1 ^= x0;
  x0 += x1; x1 = rotl32(x1, 29); x1 ^= x0;
  x0 += x1; x1 = rotl32(x1, 16); x1 ^= x0;
  x0 += x1; x1 = rotl32(x1, 24); x1 ^= x0;
  x0 += ks2; x1 += ks0 + 2u;
  x0 += x1; x1 = rotl32(x1, 13); x1 ^= x0;
  x0 += x1; x1 = rotl32(x1, 15); x1 ^= x0;
  x0 += x1; x1 = rotl32(x1, 26); x1 ^= x0;
  x0 += x1; x1 = rotl32(x1, 6);  x1 ^= x0;
  x0 += ks0; x1 += ks1 + 3u;
  x0 += x1; x1 = rotl32(x1, 17); x1 ^= x0;
  x0 += x1; x1 = rotl32(x1, 29); x1 ^= x0;
  x0 += x1; x1 = rotl32(x1, 16); x1 ^= x0;
  x0 += x1; x1 = rotl32(x1, 24); x1 ^= x0;
  x0 += ks1; x1 += ks2 + 4u;
  x0 += x1; x1 = rotl32(x1, 13); x1 ^= x0;
  x0 += x1; x1 = rotl32(x1, 15); x1 ^= x0;
  x0 += x1; x1 = rotl32(x1, 26); x1 ^= x0;
  x0 += x1; x1 = rotl32(x1, 6);  x1 ^= x0;
  x0 += ks2; x1 += ks0 + 5u;
  o0 = x0; o1 = x1;
}

__device__ __forceinline__ float jax_gumbel(uint32_t i) {
  uint32_t o0, o1;
  threefry2x32(0u, 777u, 0u, i, o0, o1);
  uint32_t bits = o0 ^ o1;
  uint32_t fb = (bits >> 9) | 0x3F800000u;
  float u = __uint_as_float(fb) - 1.0f;    // [0,1)
  float uu = fmaxf(TINYF, u + TINYF);
  return -logf(-logf(uu));
}

// ---------------- fused pipeline, one launch, 4 fence-free grid barriers ----------------
__global__ __launch_bounds__(NTHR, 2) void fused(
    const float* __restrict__ x, const float* __restrict__ sw,
    const float* __restrict__ att, const int* __restrict__ epoch_p,
    float* __restrict__ out, int* __restrict__ sync,
    double* __restrict__ scores, double* __restrict__ ball,
    double* __restrict__ logits, int* __restrict__ perm,
    float* __restrict__ sm_sort) {
  __shared__ double sc_lds[N_T];     // 24 KB, phase-2 score cache
  const int tid = threadIdx.x;
  const int lane = tid & 63;
  const int gw = blockIdx.x * WPB + (tid >> 6);   // 0..NWAVE-1

  // ---- phase 1: scores[i] = x[i].sw ; ball[i] = x[i].wb  (f64, wave per row)
  for (int i = gw; i < N_T; i += NWAVE) {
    double xv0 = (double)x[i * D_T + lane];
    double xv1 = (double)x[i * D_T + 64 + lane];
    double ps = xv0 * (double)sw[lane] + xv1 * (double)sw[64 + lane];
    double pb = xv0 * (double)att[D_T + lane] + xv1 * (double)att[D_T + 64 + lane];
    ps = wsumd(ps);
    pb = wsumd(pb);
    if (lane == 0) { ast_d(&scores[i], ps); ast_d(&ball[i], pb); }
  }
  grid_barrier(sync, 0);

  // ---- phase 2: stage scores to LDS, rank each element; if rank<K, perm[rank]=i
  for (int j = tid; j < N_T; j += NTHR) sc_lds[j] = ald_d(&scores[j]);
  __syncthreads();
  for (int i = gw; i < N_T; i += NWAVE) {
    double si = sc_lds[i];
    int cnt = 0;
#pragma unroll 8
    for (int j = lane; j < N_T; j += 64) {
      double sj = sc_lds[j];
      cnt += ((sj > si) || (sj == si && j < i)) ? 1 : 0;
    }
    cnt = wsumi(cnt);
    if (lane == 0 && cnt < K_T) ast_i(&perm[cnt], i);
  }
  grid_barrier(sync, 1);

  // ---- phase 3: per-row softmax + gk + stable rank (one wave per row)
  // Block 0 is excluded (rows start at gw==WPB) so the barrier aggregator polls
  // while the workers compute -> detection latency hidden.
  if (gw >= WPB && gw < WPB + RES_T) {
    int r = gw - WPB;
    int pr  = ald_i(&perm[r]);
    int pd0 = ald_i(&perm[r + lane]);
    int pd1 = ald_i(&perm[r + 64 + lane]);
    int pd2 = ald_i(&perm[r + 128 + lane]);

    double s0 = ald_d(&ball[pd0]), s1 = ald_d(&ball[pd1]), s2 = ald_d(&ball[pd2]);
    double mx = wmaxd(fmax(s0, fmax(s1, s2)));
    double e0 = exp(s0 - mx), e1 = exp(s1 - mx), e2 = exp(s2 - mx);
    double ssum = wsumd(e0 + e1 + e2);

    float xa = x[pr * D_T + lane];        // dims lane
    float xb = x[pr * D_T + 64 + lane];   // dims 64+lane
    const float4* r0 = (const float4*)(x + (size_t)pd0 * D_T);
    const float4* r1 = (const float4*)(x + (size_t)pd1 * D_T);
    const float4* r2 = (const float4*)(x + (size_t)pd2 * D_T);
    double sq0 = 0.0, sq1 = 0.0, sq2 = 0.0;
#pragma unroll 4
    for (int tt = 0; tt < 32; ++tt) {
      float4 v0 = r0[tt], v1 = r1[tt], v2 = r2[tt];
      float src = (tt < 16) ? xa : xb;
      int base = (tt * 4) & 63;
      float u0 = __shfl(src, base);
      float u1 = __shfl(src, base + 1);
      float u2 = __shfl(src, base + 2);
      float u3 = __shfl(src, base + 3);
      float d;
      d = u0 - v0.x; sq0 += (double)d * (double)d;
      d = u1 - v0.y; sq0 += (double)d * (double)d;
      d = u2 - v0.z; sq0 += (double)d * (double)d;
      d = u3 - v0.w; sq0 += (double)d * (double)d;
      d = u0 - v1.x; sq1 += (double)d * (double)d;
      d = u1 - v1.y; sq1 += (double)d * (double)d;
      d = u2 - v1.z; sq1 += (double)d * (double)d;
      d = u3 - v1.w; sq1 += (double)d * (double)d;
      d = u0 - v2.x; sq2 += (double)d * (double)d;
      d = u1 - v2.y; sq2 += (double)d * (double)d;
      d = u2 - v2.z; sq2 += (double)d * (double)d;
      d = u3 - v2.w; sq2 += (double)d * (double)d;
    }
    double g0v = exp(-sqrt(fmax(sq0, 1e-24)) * 0.5) - 1e-5;
    double g1v = exp(-sqrt(fmax(sq1, 1e-24)) * 0.5) - 1e-5;
    double g2v = exp(-sqrt(fmax(sq2, 1e-24)) * 0.5) - 1e-5;

    // stable descending rank among the row's 192 values (f index tie-break)
    int rk0 = 0, rk1 = 0, rk2 = 0;
#pragma unroll 4
    for (int j = 0; j < 64; ++j) {
      double h0 = __shfl(g0v, j), h1 = __shfl(g1v, j), h2 = __shfl(g2v, j);
      rk0 += ((h0 > g0v) || (h0 == g0v && j < lane)) ? 1 : 0;
      rk0 += (h1 > g0v) ? 1 : 0;
      rk0 += (h2 > g0v) ? 1 : 0;
      rk1 += ((h0 > g1v) || (h0 == g1v)) ? 1 : 0;
      rk1 += ((h1 > g1v) || (h1 == g1v && j < lane)) ? 1 : 0;
      rk1 += (h2 > g1v) ? 1 : 0;
      rk2 += ((h0 > g2v) || (h0 == g2v)) ? 1 : 0;
      rk2 += ((h1 > g2v) || (h1 == g2v)) ? 1 : 0;
      rk2 += ((h2 > g2v) || (h2 == g2v && j < lane)) ? 1 : 0;
    }
    size_t rb = (size_t)r * FS_T;
    double inv = 1.0 / ssum;
    ast_f(&out[rb + rk0], (float)g0v);  ast_f(&sm_sort[rb + rk0], (float)(e0 * inv));
    ast_f(&out[rb + rk1], (float)g1v);  ast_f(&sm_sort[rb + rk1], (float)(e1 * inv));
    ast_f(&out[rb + rk2], (float)g2v);  ast_f(&sm_sort[rb + rk2], (float)(e2 * inv));
  }
  grid_barrier(sync, 2);

  // ---- phase 4: logits[c] = sum_r sm_sort[r][c]  (wave per column; block 0 excluded)
  if (gw >= WPB && gw < WPB + FS_T) {
    int c = gw - WPB;
    double s = 0.0;
    for (int j = lane; j < RES_T; j += 64) s += (double)ald_f(&sm_sort[(size_t)j * FS_T + c]);
    s = wsumd(s);
    if (lane == 0) ast_d(&logits[c], s);
  }
  grid_barrier(sync, 3);

  // ---- phase 5: gumbel softmax * gk  (wave per row)
  if (gw < RES_T) {
    int r = gw;
    int i0 = r * FS_T + lane, i1 = i0 + 64, i2 = i0 + 128;
    float gk0 = ald_f(&out[i0]), gk1 = ald_f(&out[i1]), gk2 = ald_f(&out[i2]);
    float gb0 = jax_gumbel((uint32_t)i0);
    float gb1 = jax_gumbel((uint32_t)i1);
    float gb2 = jax_gumbel((uint32_t)i2);
    double l0 = ald_d(&logits[lane]);
    double l1 = ald_d(&logits[64 + lane]);
    double l2 = ald_d(&logits[128 + lane]);

    int ei = epoch_p[0];
    double epoch;
    if (ei >= 0 && ei <= 100000) epoch = (double)ei;
    else {
      float ef = __int_as_float(ei);
      epoch = (ef >= 0.0f && ef <= 100000.0f) ? (double)ef : 50.0;
    }
    double invtau = 0.1 * exp(0.04605170185988091 * epoch);   // 1/tau0

    float z0 = (lane == 0) ? -INFINITY : (float)(((double)gb0 + l0) * invtau);
    float z1 = (float)(((double)gb1 + l1) * invtau);
    float z2 = (float)(((double)gb2 + l2) * invtau);
    float m = wmaxf(fmaxf(z0, fmaxf(z1, z2)));
    float e0 = (lane == 0) ? 0.0f : expf(z0 - m);
    float e1 = expf(z1 - m);
    float e2 = expf(z2 - m);
    float ssum = wsumf(e0 + e1 + e2);
    float invs = 1.0f / ssum;
    out[i0] = gk0 * (e0 * invs);
    out[i1] = gk1 * (e1 * invs);
    out[i2] = gk2 * (e2 * invs);
  }
}

// ---------------- launcher ----------------
extern "C" void kernel_launch(void* const* d_in, const int* in_sizes, int n_in,
                              void* d_out, int out_size, void* d_ws, size_t ws_size,
                              hipStream_t stream) {
  const float* x   = (const float*)d_in[0];
  // d_in[1] = edge_index (unused by the reference)
  const float* sw  = (const float*)d_in[2];
  // d_in[3] = score_b (order-preserving constant shift; unused)
  const float* att = (const float*)d_in[4];
  const int* epoch = (const int*)d_in[5];
  float* out = (float*)d_out;

  char* ws = (char*)d_ws;
  int*    sync    = (int*)ws;                   // arrive[4][256] + done words: < 8 KB
  double* scores  = (double*)(ws + 8192);       // 3072
  double* ball    = scores + N_T;               // 3072
  double* logits  = ball + N_T;                 // 192
  int*    perm    = (int*)(logits + FS_T);      // 1536
  float*  sm_sort = (float*)(perm + K_T);       // 258240   (~1.1 MB total)

  (void)hipMemsetAsync(sync, 0, 8192, stream);  // reset barrier state every launch
  fused<<<NBLK, NTHR, 0, stream>>>(x, sw, att, epoch, out, sync,
                                   scores, ball, logits, perm, sm_sort);
}